// Round 3
// baseline (228.692 us; speedup 1.0000x reference)
//
#include <hip/hip_runtime.h>
#include <math.h>

#define N_NODES 10000
#define N_EDGES 160000
#define IN_FEATS 512
#define HEADS 8
#define OUT_FEATS 64
#define HF (HEADS * OUT_FEATS)   // 512
#define NEG_SLOPE 0.2f
#define M_PAD 10112              // 79 * 128

typedef float  f32x4  __attribute__((ext_vector_type(4)));
typedef __bf16 bf16x8 __attribute__((ext_vector_type(8)));
typedef short  s16x8  __attribute__((ext_vector_type(8)));

__device__ __forceinline__ void split_bf16(float x, unsigned short& h, unsigned short& l) {
    unsigned u = __float_as_uint(x);
    h = (unsigned short)(u >> 16);
    float hf = __uint_as_float(u & 0xFFFF0000u);
    l = (unsigned short)(__float_as_uint(x - hf) >> 16);
}

__device__ __forceinline__ unsigned short f2bf_rn(float x) {
    unsigned u = __float_as_uint(x);
    unsigned r = u + 0x7FFFu + ((u >> 16) & 1u);
    return (unsigned short)(r >> 16);
}

__device__ __forceinline__ float bf2f(unsigned short u) {
    return __uint_as_float(((unsigned)u) << 16);
}

__device__ __forceinline__ void gl_lds16(const void* g, void* l) {
    __builtin_amdgcn_global_load_lds((const __attribute__((address_space(1))) void*)g,
                                     (__attribute__((address_space(3))) void*)l, 16, 0, 0);
}

// ---- split feat into bf16 hi/lo planes (padded rows zeroed) + zero scratch ----
__global__ __launch_bounds__(256) void split_feat(const float* __restrict__ feat,
                                                  unsigned short* __restrict__ Ahi,
                                                  unsigned short* __restrict__ Alo,
                                                  int* __restrict__ counts2,     // counts+cursor, 2N ints
                                                  float* __restrict__ eler2) {   // el+er, 2*N*HEADS floats
    const int idx = blockIdx.x * 256 + threadIdx.x;       // one float4 per thread
    if (idx < 2 * N_NODES) counts2[idx] = 0;
    if (idx < 2 * N_NODES * HEADS) eler2[idx] = 0.f;
    const int total = M_PAD * IN_FEATS / 4;
    if (idx >= total) return;
    const int row = idx >> 7;            // / 128
    const int c4  = idx & 127;
    float4 v = make_float4(0.f, 0.f, 0.f, 0.f);
    if (row < N_NODES)
        v = *reinterpret_cast<const float4*>(feat + (size_t)row * IN_FEATS + c4 * 4);
    ushort4 hi, lo;
    split_bf16(v.x, hi.x, lo.x);
    split_bf16(v.y, hi.y, lo.y);
    split_bf16(v.z, hi.z, lo.z);
    split_bf16(v.w, hi.w, lo.w);
    size_t off = (size_t)row * IN_FEATS + c4 * 4;
    *reinterpret_cast<ushort4*>(Ahi + off) = hi;
    *reinterpret_cast<ushort4*>(Alo + off) = lo;
}

// ---- W transpose + bf16 hi/lo split: Bt[n][k] ----
#define TW 64
__global__ __launch_bounds__(256) void prep_w(const float* __restrict__ W,
                                              unsigned short* __restrict__ Bt_hi,
                                              unsigned short* __restrict__ Bt_lo) {
    __shared__ float tile[TW][TW + 1];
    const int tid = threadIdx.x;
    const int k0 = blockIdx.x * TW;
    const int n0 = blockIdx.y * TW;
    #pragma unroll
    for (int i = 0; i < 4; ++i) {
        int f = tid + 256 * i;
        int r = f >> 4, c4 = f & 15;
        float4 v = *reinterpret_cast<const float4*>(W + (size_t)(k0 + r) * HF + n0 + c4 * 4);
        tile[r][c4 * 4 + 0] = v.x;
        tile[r][c4 * 4 + 1] = v.y;
        tile[r][c4 * 4 + 2] = v.z;
        tile[r][c4 * 4 + 3] = v.w;
    }
    __syncthreads();
    #pragma unroll
    for (int i = 0; i < 4; ++i) {
        int f = tid + 256 * i;
        int rn = f >> 4, c4 = f & 15;
        ushort4 hi, lo;
        split_bf16(tile[c4 * 4 + 0][rn], hi.x, lo.x);
        split_bf16(tile[c4 * 4 + 1][rn], hi.y, lo.y);
        split_bf16(tile[c4 * 4 + 2][rn], hi.z, lo.z);
        split_bf16(tile[c4 * 4 + 3][rn], hi.w, lo.w);
        size_t off = (size_t)(n0 + rn) * IN_FEATS + k0 + c4 * 4;
        *reinterpret_cast<ushort4*>(Bt_hi + off) = hi;
        *reinterpret_cast<ushort4*>(Bt_lo + off) = lo;
    }
}

// ---- split-bf16 MFMA GEMM with global_load_lds; epilogue: bf16 h + fused el/er ----
#define GTM 128
#define GTN 64
#define GBK 32
__global__ __launch_bounds__(256) void gemm_mfma(const unsigned short* __restrict__ Ahi,
                                                 const unsigned short* __restrict__ Alo,
                                                 const unsigned short* __restrict__ Bt_hi,
                                                 const unsigned short* __restrict__ Bt_lo,
                                                 const float* __restrict__ attn_l,
                                                 const float* __restrict__ attn_r,
                                                 unsigned short* __restrict__ hbf,
                                                 float* __restrict__ el,
                                                 float* __restrict__ er) {
    __shared__ unsigned short sAhi[GTM][GBK];
    __shared__ unsigned short sAlo[GTM][GBK];
    __shared__ unsigned short sBhi[GTN][GBK];
    __shared__ unsigned short sBlo[GTN][GBK];

    const int tid  = threadIdx.x;
    const int lane = tid & 63;
    const int w    = tid >> 6;
    const int wm   = w >> 1, wn = w & 1;
    const int m16  = lane & 15, quad = lane >> 4;
    const int row0 = blockIdx.x * GTM;
    const int col0 = blockIdx.y * GTN;     // = head * 64
    const int hh   = blockIdx.y;

    // staging lane mapping: within a 1KB chunk (16 rows x 64B), lane l ->
    // row l>>2, col-shorts (l&3)*8
    const int s_r  = lane >> 2;
    const int s_c  = (lane & 3) * 8;

    f32x4 acc[4][2] = {};

    for (int k0 = 0; k0 < IN_FEATS; k0 += GBK) {
        __syncthreads();   // previous iteration's LDS reads complete
        // A planes: 8 chunks of 16 rows; wave w stages chunks 2w, 2w+1
        #pragma unroll
        for (int j = 0; j < 2; ++j) {
            const int c = w * 2 + j;
            const size_t goff = (size_t)(row0 + c * 16 + s_r) * IN_FEATS + k0 + s_c;
            gl_lds16(Ahi + goff, (unsigned short*)sAhi + c * 512);
            gl_lds16(Alo + goff, (unsigned short*)sAlo + c * 512);
        }
        // B planes: 4 chunks; wave w stages chunk w
        {
            const size_t goff = (size_t)(col0 + w * 16 + s_r) * IN_FEATS + k0 + s_c;
            gl_lds16(Bt_hi + goff, (unsigned short*)sBhi + w * 512);
            gl_lds16(Bt_lo + goff, (unsigned short*)sBlo + w * 512);
        }
        __syncthreads();   // compiler drains vmcnt before barrier

        s16x8 fah[4], fal[4], fbh[2], fbl[2];
        #pragma unroll
        for (int mi = 0; mi < 4; ++mi) {
            const int rm = wm * 64 + mi * 16 + m16;
            fah[mi] = *reinterpret_cast<const s16x8*>(&sAhi[rm][quad * 8]);
            fal[mi] = *reinterpret_cast<const s16x8*>(&sAlo[rm][quad * 8]);
        }
        #pragma unroll
        for (int ni = 0; ni < 2; ++ni) {
            const int rn = wn * 32 + ni * 16 + m16;
            fbh[ni] = *reinterpret_cast<const s16x8*>(&sBhi[rn][quad * 8]);
            fbl[ni] = *reinterpret_cast<const s16x8*>(&sBlo[rn][quad * 8]);
        }
        #pragma unroll
        for (int mi = 0; mi < 4; ++mi) {
            #pragma unroll
            for (int ni = 0; ni < 2; ++ni) {
                acc[mi][ni] = __builtin_amdgcn_mfma_f32_16x16x32_bf16(
                    __builtin_bit_cast(bf16x8, fah[mi]), __builtin_bit_cast(bf16x8, fbh[ni]),
                    acc[mi][ni], 0, 0, 0);
                acc[mi][ni] = __builtin_amdgcn_mfma_f32_16x16x32_bf16(
                    __builtin_bit_cast(bf16x8, fah[mi]), __builtin_bit_cast(bf16x8, fbl[ni]),
                    acc[mi][ni], 0, 0, 0);
                acc[mi][ni] = __builtin_amdgcn_mfma_f32_16x16x32_bf16(
                    __builtin_bit_cast(bf16x8, fal[mi]), __builtin_bit_cast(bf16x8, fbh[ni]),
                    acc[mi][ni], 0, 0, 0);
            }
        }
    }

    // epilogue: C/D layout row = quad*4 + reg, col = m16 (per-16x16 tile)
    // (a) bf16 h store  (b) fused el/er partials via in-quad reduction + atomicAdd
    float alw[2], arw[2];
    #pragma unroll
    for (int ni = 0; ni < 2; ++ni) {
        const int c = wn * 32 + ni * 16 + m16;     // 0..63 within head
        alw[ni] = attn_l[hh * OUT_FEATS + c];
        arw[ni] = attn_r[hh * OUT_FEATS + c];
    }
    #pragma unroll
    for (int mi = 0; mi < 4; ++mi) {
        #pragma unroll
        for (int r = 0; r < 4; ++r) {
            const int grow = row0 + wm * 64 + mi * 16 + quad * 4 + r;
            if (grow < N_NODES) {
                float v0 = acc[mi][0][r], v1 = acc[mi][1][r];
                const size_t cb = (size_t)grow * HF + col0 + wn * 32 + m16;
                hbf[cb]      = f2bf_rn(v0);
                hbf[cb + 16] = f2bf_rn(v1);
                float pl = v0 * alw[0] + v1 * alw[1];
                float pr = v0 * arw[0] + v1 * arw[1];
                #pragma unroll
                for (int off = 1; off < 16; off <<= 1) {
                    pl += __shfl_xor(pl, off);
                    pr += __shfl_xor(pr, off);
                }
                if (m16 == 0) {
                    atomicAdd(&el[grow * HEADS + hh], pl);
                    atomicAdd(&er[grow * HEADS + hh], pr);
                }
            }
        }
    }
}

// ---- CSR build ----
__global__ void hist_kernel(const int* __restrict__ dst, int* __restrict__ counts) {
    int e = blockIdx.x * blockDim.x + threadIdx.x;
    if (e < N_EDGES) atomicAdd(&counts[dst[e]], 1);
}

__global__ __launch_bounds__(1024) void scan_fast(const int* __restrict__ counts,
                                                  int* __restrict__ row_ptr) {
    const int t = threadIdx.x;
    const int lane = t & 63, wid = t >> 6;
    int loc[10];
    int tot = 0;
    #pragma unroll
    for (int j = 0; j < 10; ++j) {
        int idx = t * 10 + j;
        int c = (idx < N_NODES) ? counts[idx] : 0;
        loc[j] = tot;
        tot += c;
    }
    int inc = tot;
    #pragma unroll
    for (int off = 1; off < 64; off <<= 1) {
        int nb = __shfl_up(inc, off);
        if (lane >= off) inc += nb;
    }
    __shared__ int wbase[16];
    if (lane == 63) wbase[wid] = inc;
    __syncthreads();
    if (t == 0) {
        int r = 0;
        #pragma unroll
        for (int i = 0; i < 16; ++i) { int x = wbase[i]; wbase[i] = r; r += x; }
    }
    __syncthreads();
    const int base = wbase[wid] + inc - tot;
    #pragma unroll
    for (int j = 0; j < 10; ++j) {
        int idx = t * 10 + j;
        if (idx < N_NODES) row_ptr[idx] = base + loc[j];
    }
    if (t == 1023) row_ptr[N_NODES] = base + tot;
}

__global__ void scatter_kernel(const int* __restrict__ src, const int* __restrict__ dst,
                               const int* __restrict__ row_ptr, int* __restrict__ cursor,
                               int* __restrict__ ssrc) {
    int e = blockIdx.x * blockDim.x + threadIdx.x;
    if (e >= N_EDGES) return;
    int d = dst[e];
    int pos = row_ptr[d] + atomicAdd(&cursor[d], 1);
    ssrc[pos] = src[e];
}

// ---- fused edge softmax -> alpha[hh][pos] ----
__global__ __launch_bounds__(256) void softmax_kernel(const float* __restrict__ el,
                                                      const float* __restrict__ er,
                                                      const int* __restrict__ row_ptr,
                                                      const int* __restrict__ ssrc,
                                                      float* __restrict__ alpha) {
    const int gw   = (blockIdx.x * blockDim.x + threadIdx.x) >> 6;
    const int lane = threadIdx.x & 63;
    if (gw >= N_NODES * HEADS) return;
    const int n  = gw >> 3;
    const int hh = gw & 7;
    const int beg = row_ptr[n];
    const int deg = row_ptr[n + 1] - beg;
    if (deg == 0) return;
    const float ern = er[gw];
    const int* sp = ssrc + beg;
    float* ap = alpha + (size_t)hh * N_EDGES + beg;

    if (deg <= 64) {
        float e = -INFINITY;
        if (lane < deg) {
            float x = el[sp[lane] * HEADS + hh] + ern;
            e = x > 0.f ? x : NEG_SLOPE * x;
        }
        float m = e;
        #pragma unroll
        for (int off = 32; off; off >>= 1) m = fmaxf(m, __shfl_xor(m, off));
        float p = (lane < deg) ? __expf(e - m) : 0.f;
        float s = p;
        #pragma unroll
        for (int off = 32; off; off >>= 1) s += __shfl_xor(s, off);
        const float inv = 1.0f / s;
        if (lane < deg) ap[lane] = p * inv;
    } else {
        float m = -INFINITY;
        for (int i = lane; i < deg; i += 64) {
            float x = el[sp[i] * HEADS + hh] + ern;
            x = x > 0.f ? x : NEG_SLOPE * x;
            m = fmaxf(m, x);
        }
        #pragma unroll
        for (int off = 32; off; off >>= 1) m = fmaxf(m, __shfl_xor(m, off));
        float s = 0.f;
        for (int i = lane; i < deg; i += 64) {
            float x = el[sp[i] * HEADS + hh] + ern;
            x = x > 0.f ? x : NEG_SLOPE * x;
            s += __expf(x - m);
        }
        #pragma unroll
        for (int off = 32; off; off >>= 1) s += __shfl_xor(s, off);
        const float inv = 1.0f / s;
        for (int i = lane; i < deg; i += 64) {
            float x = el[sp[i] * HEADS + hh] + ern;
            x = x > 0.f ? x : NEG_SLOPE * x;
            ap[i] = __expf(x - m) * inv;
        }
    }
}

// ---- aggregation: bf16 gather + fma, 4-wide, 2 accumulators ----
__global__ __launch_bounds__(256) void aggregate_kernel(const unsigned short* __restrict__ hbf,
                                                        const float* __restrict__ alpha,
                                                        const float* __restrict__ bias,
                                                        const int* __restrict__ row_ptr,
                                                        const int* __restrict__ ssrc,
                                                        float* __restrict__ out) {
    const int gw   = (blockIdx.x * blockDim.x + threadIdx.x) >> 6;
    const int lane = threadIdx.x & 63;
    if (gw >= N_NODES * HEADS) return;
    const int n  = gw >> 3;
    const int hh = gw & 7;
    const int beg = row_ptr[n];
    const int deg = row_ptr[n + 1] - beg;
    const float bv = bias[hh * OUT_FEATS + lane];
    const size_t obase = (size_t)n * HF + hh * OUT_FEATS + lane;
    if (deg == 0) { out[obase] = bv; return; }

    const unsigned short* __restrict__ hb = hbf + hh * OUT_FEATS + lane;
    const float* __restrict__ ap = alpha + (size_t)hh * N_EDGES + beg;
    const int*   __restrict__ sp = ssrc + beg;

    float acc0 = 0.f, acc1 = 0.f;
    int k = 0;
    for (; k + 4 <= deg; k += 4) {
        int s0 = sp[k], s1 = sp[k + 1], s2 = sp[k + 2], s3 = sp[k + 3];
        float a0 = ap[k], a1 = ap[k + 1], a2 = ap[k + 2], a3 = ap[k + 3];
        float h0 = bf2f(hb[(size_t)s0 * HF]);
        float h1 = bf2f(hb[(size_t)s1 * HF]);
        float h2 = bf2f(hb[(size_t)s2 * HF]);
        float h3 = bf2f(hb[(size_t)s3 * HF]);
        acc0 = fmaf(a0, h0, acc0);
        acc1 = fmaf(a1, h1, acc1);
        acc0 = fmaf(a2, h2, acc0);
        acc1 = fmaf(a3, h3, acc1);
    }
    for (; k < deg; ++k)
        acc0 = fmaf(ap[k], bf2f(hb[(size_t)sp[k] * HF]), acc0);
    out[obase] = acc0 + acc1 + bv;
}

// ---- launch ----
extern "C" void kernel_launch(void* const* d_in, const int* in_sizes, int n_in,
                              void* d_out, int out_size, void* d_ws, size_t ws_size,
                              hipStream_t stream) {
    const float* feat   = (const float*)d_in[0];
    const float* W      = (const float*)d_in[1];
    const float* attn_l = (const float*)d_in[2];
    const float* attn_r = (const float*)d_in[3];
    const float* bias   = (const float*)d_in[4];
    const int*   src    = (const int*)d_in[5];
    const int*   dst    = (const int*)d_in[6];
    float* out = (float*)d_out;

    char* ws = (char*)d_ws;
    unsigned short* Ahi   = (unsigned short*)ws; ws += (size_t)M_PAD * IN_FEATS * 2;   // 10.35 MB
    unsigned short* Alo   = (unsigned short*)ws; ws += (size_t)M_PAD * IN_FEATS * 2;   // 10.35 MB
    unsigned short* Bt_hi = (unsigned short*)ws; ws += (size_t)IN_FEATS * HF * 2;      // 0.52 MB
    unsigned short* Bt_lo = (unsigned short*)ws; ws += (size_t)IN_FEATS * HF * 2;      // 0.52 MB
    unsigned short* hbf   = (unsigned short*)ws; ws += (size_t)N_NODES * HF * 2;       // 10.24 MB
    float*          alpha = (float*)ws;          ws += (size_t)HEADS * N_EDGES * 4;    // 5.12 MB
    float*          el_buf= (float*)ws;          ws += (size_t)N_NODES * HEADS * 4;    // el+er contiguous
    float*          er_buf= (float*)ws;          ws += (size_t)N_NODES * HEADS * 4;
    int*            counts= (int*)ws;            ws += (size_t)N_NODES * 4;            // counts+cursor contiguous
    int*            cursor= (int*)ws;            ws += (size_t)N_NODES * 4;
    int*            row_ptr=(int*)ws;            ws += (size_t)(N_NODES + 1) * 4;
    int*            ssrc  = (int*)ws;            ws += (size_t)N_EDGES * 4;

    // 1) split A planes + zero counts/cursor/el/er
    const int sf_threads = M_PAD * IN_FEATS / 4;
    split_feat<<<(sf_threads + 255) / 256, 256, 0, stream>>>(feat, Ahi, Alo, counts, el_buf);

    // 2) W transpose+split
    dim3 wgrid(IN_FEATS / TW, HF / TW);
    prep_w<<<wgrid, 256, 0, stream>>>(W, Bt_hi, Bt_lo);

    // 3) projection GEMM + fused el/er + bf16 h
    dim3 ggrid(M_PAD / GTM, HF / GTN);
    gemm_mfma<<<ggrid, 256, 0, stream>>>(Ahi, Alo, Bt_hi, Bt_lo, attn_l, attn_r,
                                         hbf, el_buf, er_buf);

    // 4) CSR by dst
    hist_kernel<<<(N_EDGES + 255) / 256, 256, 0, stream>>>(dst, counts);
    scan_fast<<<1, 1024, 0, stream>>>(counts, row_ptr);
    scatter_kernel<<<(N_EDGES + 255) / 256, 256, 0, stream>>>(src, dst, row_ptr, cursor, ssrc);

    // 5) edge softmax -> alpha
    int nwaves = N_NODES * HEADS;
    softmax_kernel<<<(nwaves * 64 + 255) / 256, 256, 0, stream>>>(el_buf, er_buf, row_ptr, ssrc, alpha);

    // 6) weighted aggregation (+bias)
    aggregate_kernel<<<(nwaves * 64 + 255) / 256, 256, 0, stream>>>(
        hbf, alpha, bias, row_ptr, ssrc, out);
}

// Round 4
// 182.068 us; speedup vs baseline: 1.2561x; 1.2561x over previous
//
#include <hip/hip_runtime.h>
#include <math.h>

#define N_NODES 10000
#define N_EDGES 160000
#define IN_FEATS 512
#define HEADS 8
#define OUT_FEATS 64
#define HF 512                   // HEADS*OUT_FEATS
#define NEG_SLOPE 0.2f
#define M_PAD 10048              // 157 * 64

typedef float  f32x4  __attribute__((ext_vector_type(4)));
typedef __bf16 bf16x8 __attribute__((ext_vector_type(8)));
typedef short  s16x8  __attribute__((ext_vector_type(8)));

__device__ __forceinline__ void split_bf16(float x, unsigned short& h, unsigned short& l) {
    unsigned u = __float_as_uint(x);
    h = (unsigned short)(u >> 16);
    float hf = __uint_as_float(u & 0xFFFF0000u);
    l = (unsigned short)(__float_as_uint(x - hf) >> 16);
}

__device__ __forceinline__ unsigned short f2bf_rn(float x) {
    unsigned u = __float_as_uint(x);
    unsigned r = u + 0x7FFFu + ((u >> 16) & 1u);
    return (unsigned short)(r >> 16);
}

__device__ __forceinline__ float bf2f(unsigned short u) {
    return __uint_as_float(((unsigned)u) << 16);
}

__device__ __forceinline__ void gl_lds16(const void* g, void* l) {
    __builtin_amdgcn_global_load_lds((const __attribute__((address_space(1))) void*)g,
                                     (__attribute__((address_space(3))) void*)l, 16, 0, 0);
}

// ---- kernel 1: zero histogram counts ----
__global__ void zero_counts(int* __restrict__ counts) {
    int i = blockIdx.x * 256 + threadIdx.x;
    if (i < N_NODES) counts[i] = 0;
}

// ---- kernel 2: prep = split_feat + prep_w + hist (sections by blockIdx) ----
#define SF_BLOCKS 5024           // M_PAD*IN_FEATS/4/256
#define PW_BLOCKS 64
#define HIST_BLOCKS 625
__global__ __launch_bounds__(256) void prep_kernel(const float* __restrict__ feat,
                                                   const float* __restrict__ W,
                                                   const int* __restrict__ dst,
                                                   unsigned short* __restrict__ Ahi,
                                                   unsigned short* __restrict__ Alo,
                                                   unsigned short* __restrict__ Bt,
                                                   int* __restrict__ counts) {
    __shared__ float tile[64][65];
    const int bid = blockIdx.x;
    const int tid = threadIdx.x;

    if (bid < SF_BLOCKS) {
        // --- split feat into bf16 hi/lo planes; pad rows [N_NODES, M_PAD) with 0 ---
        const int idx = bid * 256 + tid;         // one float4 per thread
        const int row = idx >> 7;                // / 128
        const int c4  = idx & 127;
        float4 v = make_float4(0.f, 0.f, 0.f, 0.f);
        if (row < N_NODES)
            v = *reinterpret_cast<const float4*>(feat + (size_t)row * IN_FEATS + c4 * 4);
        ushort4 hi, lo;
        split_bf16(v.x, hi.x, lo.x);
        split_bf16(v.y, hi.y, lo.y);
        split_bf16(v.z, hi.z, lo.z);
        split_bf16(v.w, hi.w, lo.w);
        size_t off = (size_t)row * IN_FEATS + c4 * 4;
        *reinterpret_cast<ushort4*>(Ahi + off) = hi;
        *reinterpret_cast<ushort4*>(Alo + off) = lo;
    } else if (bid < SF_BLOCKS + PW_BLOCKS) {
        // --- transpose W -> Bt[n][k], RN-rounded single bf16 plane ---
        const int b2 = bid - SF_BLOCKS;
        const int k0 = (b2 & 7) * 64;
        const int n0 = (b2 >> 3) * 64;
        #pragma unroll
        for (int i = 0; i < 4; ++i) {
            int f = tid + 256 * i;
            int r = f >> 4, c4 = f & 15;
            float4 v = *reinterpret_cast<const float4*>(W + (size_t)(k0 + r) * HF + n0 + c4 * 4);
            tile[r][c4 * 4 + 0] = v.x;
            tile[r][c4 * 4 + 1] = v.y;
            tile[r][c4 * 4 + 2] = v.z;
            tile[r][c4 * 4 + 3] = v.w;
        }
        __syncthreads();
        #pragma unroll
        for (int i = 0; i < 4; ++i) {
            int f = tid + 256 * i;
            int rn = f >> 4, c4 = f & 15;
            ushort4 o;
            o.x = f2bf_rn(tile[c4 * 4 + 0][rn]);
            o.y = f2bf_rn(tile[c4 * 4 + 1][rn]);
            o.z = f2bf_rn(tile[c4 * 4 + 2][rn]);
            o.w = f2bf_rn(tile[c4 * 4 + 3][rn]);
            *reinterpret_cast<ushort4*>(Bt + (size_t)(n0 + rn) * IN_FEATS + k0 + c4 * 4) = o;
        }
    } else {
        // --- degree histogram over dst ---
        const int e = (bid - SF_BLOCKS - PW_BLOCKS) * 256 + tid;
        if (e < N_EDGES) atomicAdd(&counts[dst[e]], 1);
    }
}

// ---- kernel 3: split-bf16 MFMA GEMM, dbuf + swizzled LDS, fused el/er ----
// grid (4, 157): x = head-pair (col), y = row-block -> consecutive blocks share A panel
#define GTM 64
#define GTN 128
#define GBK 32
__global__ __launch_bounds__(256) void gemm_mfma(const unsigned short* __restrict__ Ahi,
                                                 const unsigned short* __restrict__ Alo,
                                                 const unsigned short* __restrict__ Bt,
                                                 const float* __restrict__ attn_l,
                                                 const float* __restrict__ attn_r,
                                                 unsigned short* __restrict__ hbf,
                                                 float* __restrict__ el,
                                                 float* __restrict__ er) {
    __shared__ unsigned short sA[2][2][GTM * GBK];   // [buf][plane] 4 KB each
    __shared__ unsigned short sB[2][GTN * GBK];      // [buf] 8 KB each

    const int tid  = threadIdx.x;
    const int lane = tid & 63;
    const int w    = tid >> 6;
    const int wm   = w >> 1, wn = w & 1;
    const int m16  = lane & 15, quad = lane >> 4;
    const int row0 = blockIdx.y * GTM;
    const int col0 = blockIdx.x * GTN;
    const int hh   = blockIdx.x * 2 + wn;            // this wave's head

    // staging: lane l of a 16-row x 32-short chunk -> row l>>2, k-unit (l&3)^((l>>4)&3)
    const int srow  = lane >> 2;
    const int kperm = (((lane & 3) ^ ((lane >> 4) & 3))) * 8;

    f32x4 acc[2][4] = {};

    // 16 staging jobs/iter: j<8 -> A(plane j>>2, chunk j&3); j>=8 -> B(chunk j-8)
    auto stage = [&](int nb, int k0) {
        #pragma unroll
        for (int jj = 0; jj < 4; ++jj) {
            const int j = w * 4 + jj;
            if (j < 8) {
                const int pl = j >> 2, ch = j & 3;
                const unsigned short* g = (pl ? Alo : Ahi)
                    + (size_t)(row0 + ch * 16 + srow) * IN_FEATS + k0 + kperm;
                gl_lds16(g, &sA[nb][pl][ch * 512]);
            } else {
                const int ch = j - 8;
                const unsigned short* g = Bt
                    + (size_t)(col0 + ch * 16 + srow) * IN_FEATS + k0 + kperm;
                gl_lds16(g, &sB[nb][ch * 512]);
            }
        }
    };

    stage(0, 0);
    int nb = 0;
    const int asw = (quad ^ ((m16 >> 2) & 3)) * 8;   // read-side swizzle

    for (int kt = 0; kt < 16; ++kt) {
        __syncthreads();                              // drain vmcnt -> buf nb ready
        if (kt < 15) stage(nb ^ 1, (kt + 1) * GBK);   // prefetch next into other buf

        s16x8 fh[2], fl[2], fb[4];
        #pragma unroll
        for (int mi = 0; mi < 2; ++mi) {
            const int base = (wm * 2 + mi) * 512 + m16 * 32 + asw;
            fh[mi] = *reinterpret_cast<const s16x8*>(&sA[nb][0][base]);
            fl[mi] = *reinterpret_cast<const s16x8*>(&sA[nb][1][base]);
        }
        #pragma unroll
        for (int ni = 0; ni < 4; ++ni) {
            const int base = (wn * 4 + ni) * 512 + m16 * 32 + asw;
            fb[ni] = *reinterpret_cast<const s16x8*>(&sB[nb][base]);
        }
        #pragma unroll
        for (int mi = 0; mi < 2; ++mi) {
            #pragma unroll
            for (int ni = 0; ni < 4; ++ni) {
                acc[mi][ni] = __builtin_amdgcn_mfma_f32_16x16x32_bf16(
                    __builtin_bit_cast(bf16x8, fh[mi]), __builtin_bit_cast(bf16x8, fb[ni]),
                    acc[mi][ni], 0, 0, 0);
                acc[mi][ni] = __builtin_amdgcn_mfma_f32_16x16x32_bf16(
                    __builtin_bit_cast(bf16x8, fl[mi]), __builtin_bit_cast(bf16x8, fb[ni]),
                    acc[mi][ni], 0, 0, 0);
            }
        }
        nb ^= 1;
    }

    // epilogue: C/D row = quad*4 + r (A side), col = m16 (B side)
    // wave covers the FULL head -> direct el/er stores, no atomics
    float alw[4], arw[4];
    #pragma unroll
    for (int ni = 0; ni < 4; ++ni) {
        const int c = ni * 16 + m16;
        alw[ni] = attn_l[hh * OUT_FEATS + c];
        arw[ni] = attn_r[hh * OUT_FEATS + c];
    }
    #pragma unroll
    for (int mi = 0; mi < 2; ++mi) {
        #pragma unroll
        for (int r = 0; r < 4; ++r) {
            const int row = row0 + wm * 32 + mi * 16 + quad * 4 + r;
            if (row < N_NODES) {
                float pl = 0.f, pr = 0.f;
                #pragma unroll
                for (int ni = 0; ni < 4; ++ni) {
                    const float v = acc[mi][ni][r];
                    hbf[(size_t)row * HF + hh * OUT_FEATS + ni * 16 + m16] = f2bf_rn(v);
                    pl = fmaf(v, alw[ni], pl);
                    pr = fmaf(v, arw[ni], pr);
                }
                #pragma unroll
                for (int off = 1; off < 16; off <<= 1) {
                    pl += __shfl_xor(pl, off);
                    pr += __shfl_xor(pr, off);
                }
                if (m16 == 0) {
                    el[row * HEADS + hh] = pl;
                    er[row * HEADS + hh] = pr;
                }
            }
        }
    }
}

// ---- kernel 4: single-block scan (row_ptr) + cursor zeroing ----
__global__ __launch_bounds__(1024) void scan_fast(const int* __restrict__ counts,
                                                  int* __restrict__ row_ptr,
                                                  int* __restrict__ cursor) {
    const int t = threadIdx.x;
    const int lane = t & 63, wid = t >> 6;
    for (int i = t; i < N_NODES; i += 1024) cursor[i] = 0;
    int loc[10];
    int tot = 0;
    #pragma unroll
    for (int j = 0; j < 10; ++j) {
        int idx = t * 10 + j;
        int c = (idx < N_NODES) ? counts[idx] : 0;
        loc[j] = tot;
        tot += c;
    }
    int inc = tot;
    #pragma unroll
    for (int off = 1; off < 64; off <<= 1) {
        int nb = __shfl_up(inc, off);
        if (lane >= off) inc += nb;
    }
    __shared__ int wbase[16];
    if (lane == 63) wbase[wid] = inc;
    __syncthreads();
    if (t == 0) {
        int r = 0;
        #pragma unroll
        for (int i = 0; i < 16; ++i) { int x = wbase[i]; wbase[i] = r; r += x; }
    }
    __syncthreads();
    const int base = wbase[wid] + inc - tot;
    #pragma unroll
    for (int j = 0; j < 10; ++j) {
        int idx = t * 10 + j;
        if (idx < N_NODES) row_ptr[idx] = base + loc[j];
    }
    if (t == 1023) row_ptr[N_NODES] = base + tot;
}

// ---- kernel 5: scatter edges into CSR order ----
__global__ void scatter_kernel(const int* __restrict__ src, const int* __restrict__ dst,
                               const int* __restrict__ row_ptr, int* __restrict__ cursor,
                               int* __restrict__ ssrc) {
    int e = blockIdx.x * blockDim.x + threadIdx.x;
    if (e >= N_EDGES) return;
    int d = dst[e];
    int pos = row_ptr[d] + atomicAdd(&cursor[d], 1);
    ssrc[pos] = src[e];
}

// ---- kernel 6: fused softmax + aggregation, one wave per (node, head) ----
__global__ __launch_bounds__(256) void aggregate_kernel(const unsigned short* __restrict__ hbf,
                                                        const float* __restrict__ el,
                                                        const float* __restrict__ er,
                                                        const float* __restrict__ bias,
                                                        const int* __restrict__ row_ptr,
                                                        const int* __restrict__ ssrc,
                                                        float* __restrict__ out) {
    const int gw   = (blockIdx.x * blockDim.x + threadIdx.x) >> 6;
    const int lane = threadIdx.x & 63;
    if (gw >= N_NODES * HEADS) return;
    const int n  = gw >> 3;
    const int hh = gw & 7;
    const int beg = row_ptr[n];
    const int deg = row_ptr[n + 1] - beg;
    const float bv = bias[hh * OUT_FEATS + lane];
    const size_t obase = (size_t)n * HF + hh * OUT_FEATS + lane;
    if (deg == 0) { out[obase] = bv; return; }

    const float ern = er[gw];
    const int* __restrict__ sp = ssrc + beg;
    const unsigned short* __restrict__ hb = hbf + hh * OUT_FEATS + lane;

    float acc0 = 0.f, acc1 = 0.f;

    if (deg <= 64) {
        // softmax in registers: lane k holds edge k's (src, alpha)
        const int s_l = (lane < deg) ? sp[lane] : 0;
        float x = -INFINITY;
        if (lane < deg) {
            float v = el[s_l * HEADS + hh] + ern;
            x = v > 0.f ? v : NEG_SLOPE * v;
        }
        float m = x;
        #pragma unroll
        for (int off = 32; off; off >>= 1) m = fmaxf(m, __shfl_xor(m, off));
        float p = (lane < deg) ? __expf(x - m) : 0.f;
        float s = p;
        #pragma unroll
        for (int off = 32; off; off >>= 1) s += __shfl_xor(s, off);
        const float a_l = p * (1.0f / s);

        int k = 0;
        for (; k + 4 <= deg; k += 4) {
            int s0 = __shfl(s_l, k),     s1 = __shfl(s_l, k + 1);
            int s2 = __shfl(s_l, k + 2), s3 = __shfl(s_l, k + 3);
            float a0 = __shfl(a_l, k),     a1 = __shfl(a_l, k + 1);
            float a2 = __shfl(a_l, k + 2), a3 = __shfl(a_l, k + 3);
            float h0 = bf2f(hb[(size_t)s0 * HF]);
            float h1 = bf2f(hb[(size_t)s1 * HF]);
            float h2 = bf2f(hb[(size_t)s2 * HF]);
            float h3 = bf2f(hb[(size_t)s3 * HF]);
            acc0 = fmaf(a0, h0, acc0);
            acc1 = fmaf(a1, h1, acc1);
            acc0 = fmaf(a2, h2, acc0);
            acc1 = fmaf(a3, h3, acc1);
        }
        for (; k < deg; ++k) {
            int sk = __shfl(s_l, k);
            float ak = __shfl(a_l, k);
            acc0 = fmaf(ak, bf2f(hb[(size_t)sk * HF]), acc0);
        }
    } else {
        // generic fallback (deg > 64): two-pass softmax, recompute in gather
        float m = -INFINITY;
        for (int i = lane; i < deg; i += 64) {
            float v = el[sp[i] * HEADS + hh] + ern;
            v = v > 0.f ? v : NEG_SLOPE * v;
            m = fmaxf(m, v);
        }
        #pragma unroll
        for (int off = 32; off; off >>= 1) m = fmaxf(m, __shfl_xor(m, off));
        float s = 0.f;
        for (int i = lane; i < deg; i += 64) {
            float v = el[sp[i] * HEADS + hh] + ern;
            v = v > 0.f ? v : NEG_SLOPE * v;
            s += __expf(v - m);
        }
        #pragma unroll
        for (int off = 32; off; off >>= 1) s += __shfl_xor(s, off);
        const float inv = 1.0f / s;
        for (int k = 0; k < deg; ++k) {
            const int sk = sp[k];
            float v = el[sk * HEADS + hh] + ern;
            v = v > 0.f ? v : NEG_SLOPE * v;
            acc0 = fmaf(__expf(v - m) * inv, bf2f(hb[(size_t)sk * HF]), acc0);
        }
    }
    out[obase] = acc0 + acc1 + bv;
}

// ---- launch ----
extern "C" void kernel_launch(void* const* d_in, const int* in_sizes, int n_in,
                              void* d_out, int out_size, void* d_ws, size_t ws_size,
                              hipStream_t stream) {
    const float* feat   = (const float*)d_in[0];
    const float* W      = (const float*)d_in[1];
    const float* attn_l = (const float*)d_in[2];
    const float* attn_r = (const float*)d_in[3];
    const float* bias   = (const float*)d_in[4];
    const int*   src    = (const int*)d_in[5];
    const int*   dst    = (const int*)d_in[6];
    float* out = (float*)d_out;

    char* ws = (char*)d_ws;
    unsigned short* Ahi    = (unsigned short*)ws; ws += (size_t)M_PAD * IN_FEATS * 2;  // 10.29 MB
    unsigned short* Alo    = (unsigned short*)ws; ws += (size_t)M_PAD * IN_FEATS * 2;  // 10.29 MB
    unsigned short* Bt     = (unsigned short*)ws; ws += (size_t)IN_FEATS * HF * 2;     // 0.52 MB
    unsigned short* hbf    = (unsigned short*)ws; ws += (size_t)N_NODES * HF * 2;      // 10.24 MB
    float*          el_buf = (float*)ws;          ws += (size_t)N_NODES * HEADS * 4;
    float*          er_buf = (float*)ws;          ws += (size_t)N_NODES * HEADS * 4;
    int*            counts = (int*)ws;            ws += (size_t)N_NODES * 4;
    int*            cursor = (int*)ws;            ws += (size_t)N_NODES * 4;
    int*            row_ptr= (int*)ws;            ws += (size_t)(N_NODES + 1) * 4;
    int*            ssrc   = (int*)ws;            ws += (size_t)N_EDGES * 4;

    // 1) zero hist counts
    zero_counts<<<(N_NODES + 255) / 256, 256, 0, stream>>>(counts);

    // 2) prep: feat split + W transpose/round + dst histogram
    prep_kernel<<<SF_BLOCKS + PW_BLOCKS + HIST_BLOCKS, 256, 0, stream>>>(
        feat, W, dst, Ahi, Alo, Bt, counts);

    // 3) projection GEMM + fused el/er + bf16 h
    dim3 ggrid(HF / GTN, M_PAD / GTM);   // (4, 157), col-fastest for A-panel L2 locality
    gemm_mfma<<<ggrid, 256, 0, stream>>>(Ahi, Alo, Bt, attn_l, attn_r, hbf, el_buf, er_buf);

    // 4) scan -> row_ptr (+ cursor zero)
    scan_fast<<<1, 1024, 0, stream>>>(counts, row_ptr, cursor);

    // 5) CSR scatter
    scatter_kernel<<<(N_EDGES + 255) / 256, 256, 0, stream>>>(src, dst, row_ptr, cursor, ssrc);

    // 6) fused edge-softmax + aggregation (+bias)
    aggregate_kernel<<<(N_NODES * HEADS * 64 + 255) / 256, 256, 0, stream>>>(
        hbf, el_buf, er_buf, bias, row_ptr, ssrc, out);
}